// Round 6
// baseline (101.708 us; speedup 1.0000x reference)
//
#include <hip/hip_runtime.h>
#include <hip/hip_bf16.h>

#define SEQ 2048
#define QSTR 4096
// (1/sqrt(128)) * log2(e)
#define CSCALE 0.1275174364688796f

typedef __attribute__((ext_vector_type(8)))  short short8;
typedef __attribute__((ext_vector_type(4)))  float f32x4;
typedef __attribute__((ext_vector_type(16))) float f32x16;

union PF8 { unsigned u[4]; short8 s; };

__device__ __forceinline__ unsigned short f2bf(float f) {
    union { __hip_bfloat16 b; unsigned short u; } cv;
    cv.b = __float2bfloat16(f);
    return cv.u;
}

__device__ __forceinline__ void gload16(const unsigned short* g, unsigned short* l) {
    __builtin_amdgcn_global_load_lds(
        (const __attribute__((address_space(1))) void*)g,
        (__attribute__((address_space(3))) void*)l, 16, 0, 0);
}

// ---- prepass: K -> bf16 [hk][kv][d] ----
__global__ void prep_k(const float* __restrict__ Kg, unsigned short* __restrict__ Kb) {
    int gi = blockIdx.x * 256 + threadIdx.x;
    int kv = gi >> 8;
    int rem = gi & 255;
    int hk = rem >> 5;
    int d4 = rem & 31;
    f32x4 k4 = *(const f32x4*)(Kg + ((size_t)kv * 8 + hk) * 128 + 4 * d4);
    ushort4 u = make_ushort4(f2bf(k4[0]), f2bf(k4[1]), f2bf(k4[2]), f2bf(k4[3]));
    *(ushort4*)(Kb + ((size_t)hk * SEQ + kv) * 128 + 4 * d4) = u;
}

// ---- prepass: V -> bf16 transposed [hk][d][kv] ----
__global__ void prep_v(const float* __restrict__ Vg, unsigned short* __restrict__ Vtb) {
    const int hk  = blockIdx.x >> 5;
    const int kvb = blockIdx.x & 31;
    __shared__ unsigned short T[128][72];
    const int t = threadIdx.x;
    #pragma unroll
    for (int i = 0; i < 8; ++i) {
        int idx = t + 256 * i;
        int r = idx >> 5, d4 = idx & 31;
        f32x4 v = *(const f32x4*)(Vg + ((size_t)(kvb * 64 + r) * 8 + hk) * 128 + 4 * d4);
        T[4 * d4 + 0][r] = f2bf(v[0]);
        T[4 * d4 + 1][r] = f2bf(v[1]);
        T[4 * d4 + 2][r] = f2bf(v[2]);
        T[4 * d4 + 3][r] = f2bf(v[3]);
    }
    __syncthreads();
    #pragma unroll
    for (int i = 0; i < 8; ++i) {
        int idx = t + 256 * i;
        int d = idx >> 4, c4 = idx & 15;
        ushort4 u = *(ushort4*)&T[d][4 * c4];
        *(ushort4*)(Vtb + ((size_t)hk * 128 + d) * SEQ + kvb * 64 + 4 * c4) = u;
    }
}

__launch_bounds__(128, 2)
__global__ void attn_fwd(const float* __restrict__ Qg,
                         const unsigned short* __restrict__ Kb,
                         const unsigned short* __restrict__ Vtb,
                         float* __restrict__ Og) {
    const int bid = blockIdx.x;
    const int g   = bid >> 5;          // 0..31
    const int h   = bid & 31;
    const int hk  = h >> 2;
    // balanced mapping: co-resident gidx {g, g+8, g+16, g+24} -> qb sums 62
    int qb;
    if      (g < 8)  qb = 31 - g;      // 31..24 (heavy first)
    else if (g < 16) qb = g - 8;       // 0..7
    else if (g < 24) qb = 39 - g;      // 23..16
    else             qb = g - 16;      // 8..15

    const int tid  = threadIdx.x;
    const int w    = tid >> 6;         // wave 0..1
    const int lane = tid & 63;
    const int q5   = lane & 31;
    const int t5   = lane >> 5;
    const int swz  = lane & 7;

    __shared__ __align__(16) unsigned char smem[32768];
    typedef unsigned short KsT[32][128];
    typedef unsigned short VtT[64][64];   // packed: col = (d>=64)*32 + kv
    KsT* Ks = (KsT*)smem;                 // 2 x 8 KB
    VtT* Vt = (VtT*)(smem + 16384);       // 2 x 8 KB
    float (*Ot)[132] = (float(*)[132])smem;  // epilogue reuse (16.9 KB)

    const int q0w = qb * 64 + 32 * w;
    const int nt  = 2 * qb + 2;

    // ---- Q fragments (B operand: col=q5, k=16st+8t5+i), scale folded ----
    short8 qf[8];
    {
        const float* qp = Qg + (size_t)(q0w + q5) * QSTR + h * 128 + 8 * t5;
        #pragma unroll
        for (int st = 0; st < 8; ++st) {
            f32x4 a = *(const f32x4*)(qp + 16 * st);
            f32x4 b = *(const f32x4*)(qp + 16 * st + 4);
            short8 f;
            f[0] = (short)f2bf(a[0] * CSCALE); f[1] = (short)f2bf(a[1] * CSCALE);
            f[2] = (short)f2bf(a[2] * CSCALE); f[3] = (short)f2bf(a[3] * CSCALE);
            f[4] = (short)f2bf(b[0] * CSCALE); f[5] = (short)f2bf(b[1] * CSCALE);
            f[6] = (short)f2bf(b[2] * CSCALE); f[7] = (short)f2bf(b[3] * CSCALE);
            qf[st] = f;
        }
    }
    #pragma unroll
    for (int st = 0; st < 8; ++st) asm volatile("" :: "v"(qf[st]));
    asm volatile("s_waitcnt vmcnt(0)" ::: "memory");

    f32x16 oacc[4];
    #pragma unroll
    for (int dt = 0; dt < 4; ++dt)
        #pragma unroll
        for (int r = 0; r < 16; ++r) oacc[dt][r] = 0.f;
    float m = -1e30f, l = 0.f;

    // staging: wave w -> K rows 16w..+15 (4 instr), V LDS rows 32w..+31 (4 instr)
    auto ISSUE = [&](int t, int b) {
        const int kv0 = t * 32;
        #pragma unroll
        for (int p = 0; p < 4; ++p) {
            int row = 16 * w + 4 * p + (lane >> 4);
            const unsigned short* gp = Kb +
                ((size_t)hk * SEQ + kv0 + row) * 128 + 8 * ((lane & 15) ^ (row & 7));
            gload16(gp, &Ks[b][16 * w + 4 * p][0]);
        }
        #pragma unroll
        for (int p = 0; p < 4; ++p) {
            int d2 = 32 * w + 8 * p + (lane >> 3);       // LDS row
            int c  = (lane & 7) ^ (d2 & 7);              // source col-group
            int d  = d2 + 64 * (c >> 2);
            const unsigned short* gp = Vtb +
                ((size_t)hk * 128 + d) * SEQ + kv0 + 8 * (c & 3);
            gload16(gp, &Vt[b][32 * w + 8 * p][0]);
        }
    };

    ISSUE(0, 0);
    ISSUE(1, 1);

    for (int t = 0; t < nt; ++t) {
        const int kv0 = t * 32;
        const int buf = t & 1;
        if (t + 1 < nt) asm volatile("s_waitcnt vmcnt(8)" ::: "memory");
        else            asm volatile("s_waitcnt vmcnt(0)" ::: "memory");
        __builtin_amdgcn_s_barrier();

        const bool active = (kv0 <= q0w + 31);
        if (active) {
            // ---- S^T = K Q^T : D[row=kv][col=q5] ----
            f32x16 sac;
            #pragma unroll
            for (int r = 0; r < 16; ++r) sac[r] = 0.f;
            __builtin_amdgcn_s_setprio(1);
            #pragma unroll
            for (int st = 0; st < 8; ++st) {
                short8 kf = *(const short8*)&Ks[buf][q5][8 * ((2 * st + t5) ^ swz)];
                sac = __builtin_amdgcn_mfma_f32_32x32x16_bf16(kf, qf[st], sac, 0, 0, 0);
            }
            __builtin_amdgcn_s_setprio(0);

            // ---- mask (single diagonal tile per wave) ----
            if (kv0 + 31 > q0w) {
                const int qrow = q0w + q5;
                #pragma unroll
                for (int r = 0; r < 16; ++r) {
                    int kv = kv0 + (r & 3) + 8 * (r >> 2) + 4 * t5;
                    if (kv > qrow) sac[r] = -1e30f;
                }
            }

            // ---- row max: depth-4 tree + one cross-lane ----
            float m8[8], m4[4], m2[2];
            #pragma unroll
            for (int i = 0; i < 8; ++i) m8[i] = fmaxf(sac[i], sac[i + 8]);
            #pragma unroll
            for (int i = 0; i < 4; ++i) m4[i] = fmaxf(m8[i], m8[i + 4]);
            m2[0] = fmaxf(m4[0], m4[2]); m2[1] = fmaxf(m4[1], m4[3]);
            float mx = fmaxf(m2[0], m2[1]);
            mx = fmaxf(mx, __shfl_xor(mx, 32));

            // ---- defer-max (T13) ----
            const bool skip = __all(mx <= m + 11.0f);
            float fac = 1.0f;
            if (!skip) {
                float mn = fmaxf(m, mx);
                fac = exp2f(m - mn);
                m = mn;
            }

            // ---- P = 2^(S-m); depth-4 tree sum ----
            #pragma unroll
            for (int r = 0; r < 16; ++r) sac[r] = exp2f(sac[r] - m);
            float s8[8], s4[4], s2[2];
            #pragma unroll
            for (int i = 0; i < 8; ++i) s8[i] = sac[i] + sac[i + 8];
            #pragma unroll
            for (int i = 0; i < 4; ++i) s4[i] = s8[i] + s8[i + 4];
            s2[0] = s4[0] + s4[2]; s2[1] = s4[1] + s4[3];
            float ps = s2[0] + s2[1];
            ps += __shfl_xor(ps, 32);
            if (!skip) {
                l = l * fac + ps;
                #pragma unroll
                for (int dt = 0; dt < 4; ++dt)
                    #pragma unroll
                    for (int r = 0; r < 16; ++r) oacc[dt][r] *= fac;
            } else {
                l += ps;
            }

            // ---- pack P pairs to bf16x2 ----
            unsigned pkw[8];
            #pragma unroll
            for (int rp = 0; rp < 8; ++rp)
                pkw[rp] = (unsigned)f2bf(sac[2 * rp]) |
                          ((unsigned)f2bf(sac[2 * rp + 1]) << 16);

            // ---- redistribute to PV B-fragments (cross-half only) ----
            unsigned xp[8];
            #pragma unroll
            for (int i = 0; i < 8; ++i)
                xp[i] = (unsigned)__shfl_xor((int)pkw[i], 32);

            PF8 pf[2];
            #pragma unroll
            for (int ks = 0; ks < 2; ++ks) {
                #pragma unroll
                for (int j = 0; j < 4; ++j) {
                    const int ib = (j & 1) + 4 * ks;
                    const unsigned own_lo = pkw[ib];
                    const unsigned own_hi = pkw[ib + 2];
                    const unsigned par_lo = xp[ib];
                    const unsigned par_hi = xp[ib + 2];
                    pf[ks].u[j] = (j < 2) ? (t5 ? par_hi : own_lo)
                                          : (t5 ? own_hi : par_lo);
                }
            }

            // ---- O^T += V^T P ----
            __builtin_amdgcn_s_setprio(1);
            #pragma unroll
            for (int dt = 0; dt < 4; ++dt) {
                #pragma unroll
                for (int ks = 0; ks < 2; ++ks) {
                    short8 vf = *(const short8*)
                        &Vt[buf][32 * (dt & 1) + q5]
                           [8 * (((dt >> 1) * 4 + 2 * ks + t5) ^ swz)];
                    oacc[dt] = __builtin_amdgcn_mfma_f32_32x32x16_bf16(vf, pf[ks].s, oacc[dt], 0, 0, 0);
                }
            }
            __builtin_amdgcn_s_setprio(0);
        }

        asm volatile("" ::: "memory");
        __builtin_amdgcn_s_barrier();
        if (t + 2 < nt) ISSUE(t + 2, buf);
    }

    // ---- epilogue: 2-pass transpose through LDS, coalesced stores ----
    asm volatile("" ::: "memory");
    const float rl = 1.0f / l;
    #pragma unroll
    for (int pass = 0; pass < 2; ++pass) {
        if (w == pass) {
            #pragma unroll
            for (int dt = 0; dt < 4; ++dt)
                #pragma unroll
                for (int rq = 0; rq < 4; ++rq) {
                    f32x4 v;
                    v[0] = oacc[dt][4 * rq + 0] * rl;
                    v[1] = oacc[dt][4 * rq + 1] * rl;
                    v[2] = oacc[dt][4 * rq + 2] * rl;
                    v[3] = oacc[dt][4 * rq + 3] * rl;
                    *(f32x4*)&Ot[q5][32 * dt + 8 * rq + 4 * t5] = v;
                }
        }
        __syncthreads();
        {
            float* ob = Og + (size_t)(qb * 64 + pass * 32) * QSTR + h * 128;
            #pragma unroll
            for (int i = 0; i < 8; ++i) {
                int u = tid + 128 * i;            // 0..1023
                int row = u >> 5, c4 = (u & 31) * 4;
                f32x4 v = *(const f32x4*)&Ot[row][c4];
                *(f32x4*)(ob + (size_t)row * QSTR + c4) = v;
            }
        }
        __syncthreads();
    }
}

extern "C" void kernel_launch(void* const* d_in, const int* in_sizes, int n_in,
                              void* d_out, int out_size, void* d_ws, size_t ws_size,
                              hipStream_t stream) {
    const float* q = (const float*)d_in[0];
    const float* k = (const float*)d_in[1];
    const float* v = (const float*)d_in[2];
    float* out = (float*)d_out;
    unsigned short* Kb  = (unsigned short*)d_ws;          // 4 MB
    unsigned short* Vtb = Kb + (size_t)8 * SEQ * 128;     // 4 MB
    prep_k<<<dim3(2048), 256, 0, stream>>>(k, Kb);
    prep_v<<<dim3(256), 256, 0, stream>>>(v, Vtb);
    attn_fwd<<<dim3(1024), 128, 0, stream>>>(q, Kb, Vtb, out);
}